// Round 7
// baseline (229.552 us; speedup 1.0000x reference)
//
#include <hip/hip_runtime.h>
#include <hip/hip_bf16.h>
#include <math.h>

typedef __hip_bfloat16 bf16;
typedef __bf16 bf16x8 __attribute__((ext_vector_type(8)));
typedef float  f32x4  __attribute__((ext_vector_type(4)));

#define NB 8
#define SL 1024
#define DD 256
#define NF 11
#define RPB 8

#define AS_G __attribute__((address_space(1)))
#define AS_L __attribute__((address_space(3)))

// ---------- fragment loaders: 8 contiguous K-elements -> bf16x8 ----------
__device__ __forceinline__ bf16x8 ldfrag(const bf16* p) {
  return *reinterpret_cast<const bf16x8*>(p);
}
__device__ __forceinline__ bf16x8 ldfrag(const float* p) {
  const float4 a = *reinterpret_cast<const float4*>(p);
  const float4 b = *reinterpret_cast<const float4*>(p + 4);
  bf16x8 r;
  r[0] = (__bf16)a.x; r[1] = (__bf16)a.y; r[2] = (__bf16)a.z; r[3] = (__bf16)a.w;
  r[4] = (__bf16)b.x; r[5] = (__bf16)b.y; r[6] = (__bf16)b.z; r[7] = (__bf16)b.w;
  return r;
}
__device__ __forceinline__ unsigned short us(float f) {
  bf16 h = __float2bfloat16(f);
  return *reinterpret_cast<unsigned short*>(&h);
}

// ---------- sync stage (f32 source): VGPR convert, XOR-swizzled LDS ----------
__device__ __forceinline__ void stage_any(const float* __restrict__ g, int ld,
                                          bf16* __restrict__ s, int tid) {
#pragma unroll
  for (int it = 0; it < 4; ++it) {
    const int cid = it * 256 + tid;
    const int row = cid >> 3, c16 = cid & 7;
    bf16x8 v = ldfrag(g + (size_t)row * ld + c16 * 8);
    *reinterpret_cast<bf16x8*>(s + row * 64 + ((c16 ^ (row & 7)) << 3)) = v;
  }
}

// ---------- async stage (bf16 source): global_load_lds dwordx4 ----------
__device__ __forceinline__ void stage_any(const bf16* __restrict__ g, int ld,
                                          bf16* __restrict__ s, int tid) {
  const int wbase = tid & ~63;           // wave-uniform
#pragma unroll
  for (int it = 0; it < 4; ++it) {
    const int cid = it * 256 + tid;
    const int row = cid >> 3, sc = cid & 7;
    const int c16 = sc ^ (row & 7);
    const bf16* src = g + (size_t)row * ld + c16 * 8;
    bf16* dst = s + (size_t)(it * 256 + wbase) * 8;   // wave-uniform base
    __builtin_amdgcn_global_load_lds((const AS_G void*)src, (AS_L void*)dst, 16, 0, 0);
  }
}

// ---------- 4 waves x (64x64) from sA[128x64] x sB[128x64] ----------
__device__ __forceinline__ void compute_tiles(const bf16* __restrict__ sA,
                                              const bf16* __restrict__ sB,
                                              int lane, int wave, f32x4 acc[4][4]) {
  const int n15 = lane & 15, quad = lane >> 4;
  const int wm = (wave >> 1) * 64, wn = (wave & 1) * 64;
#pragma unroll
  for (int kc = 0; kc < 2; ++kc) {
    const int c16 = kc * 4 + quad;
    bf16x8 aF[4], bF[4];
#pragma unroll
    for (int t = 0; t < 4; ++t) {
      const int ra = wm + t * 16 + n15;
      aF[t] = *reinterpret_cast<const bf16x8*>(sA + ra * 64 + ((c16 ^ (ra & 7)) << 3));
      const int rb = wn + t * 16 + n15;
      bF[t] = *reinterpret_cast<const bf16x8*>(sB + rb * 64 + ((c16 ^ (rb & 7)) << 3));
    }
#pragma unroll
    for (int ti = 0; ti < 4; ++ti)
#pragma unroll
      for (int tj = 0; tj < 4; ++tj)
        acc[ti][tj] = __builtin_amdgcn_mfma_f32_16x16x32_bf16(aF[ti], bF[tj], acc[ti][tj], 0, 0, 0);
  }
}

// ---------- double-buffered block GEMM: C(128x128) += A(128xK) * B(128xK)^T ----------
// one barrier per K-chunk; next chunk's staging overlaps current compute
template<typename TA, typename TB>
__device__ __forceinline__ void gemm_core(const TA* __restrict__ A, int lda,
                                          const TB* __restrict__ B, int ldb, int K,
                                          bf16* s, int tid, f32x4 acc[4][4]) {
  const int lane = tid & 63, wave = tid >> 6;
  bf16* bufA[2] = { s,         s + 16384 };
  bf16* bufB[2] = { s + 8192,  s + 24576 };
  stage_any(A, lda, bufA[0], tid);
  stage_any(B, ldb, bufB[0], tid);
  int cur = 0;
  for (int k0 = 0; k0 < K; k0 += 64) {
    __syncthreads();                       // cur buffer DMA drained; prev compute done
    if (k0 + 64 < K) {
      stage_any(A + k0 + 64, lda, bufA[cur ^ 1], tid);   // overlaps compute below
      stage_any(B + k0 + 64, ldb, bufB[cur ^ 1], tid);
    }
    compute_tiles(bufA[cur], bufB[cur], lane, wave, acc);
    cur ^= 1;
  }
}

__device__ __forceinline__ float wred_sum(float v) {
#pragma unroll
  for (int o = 32; o > 0; o >>= 1) v += __shfl_xor(v, o, 64);
  return v;
}

// ---------- K1: 5 fused projections; qp/kp land in concatenated qq/kk (ld 512) ----------
__global__ __launch_bounds__(256) void k_proj(
    const float* __restrict__ q, const float* __restrict__ k, const float* __restrict__ v,
    const float* __restrict__ wqs, const float* __restrict__ wks, const float* __restrict__ wvs,
    const float* __restrict__ wqs2, const float* __restrict__ wks2,
    bf16* __restrict__ qq, bf16* __restrict__ kk,
    bf16* __restrict__ vpt, bf16* __restrict__ q2t, bf16* __restrict__ k2t)
{
  __shared__ bf16 smem[4 * 128 * 64];
  const int tid = threadIdx.x, lane = tid & 63, wave = tid >> 6;
  const int z = blockIdx.z;
  const float* A = (z == 2) ? v : ((z == 1 || z == 4) ? k : q);
  const float* W = (z == 0) ? wqs : (z == 1) ? wks : (z == 2) ? wvs : (z == 3) ? wqs2 : wks2;
  const int rowBase = blockIdx.x * 128;
  const int colBase = blockIdx.y * 128;
  f32x4 acc[4][4] = {};
  gemm_core(A + (size_t)rowBase * DD, DD, W + (size_t)colBase * DD, DD, DD, smem, tid, acc);
  const int n15 = lane & 15, quad = lane >> 4;
  const int wm = (wave >> 1) * 64, wn = (wave & 1) * 64;
  if (z <= 1) {
    bf16* O = (z == 0) ? qq : kk;
#pragma unroll
    for (int ti = 0; ti < 4; ++ti)
#pragma unroll
      for (int tj = 0; tj < 4; ++tj)
#pragma unroll
        for (int r = 0; r < 4; ++r) {
          int row = rowBase + wm + ti * 16 + quad * 4 + r;
          int col = colBase + wn + tj * 16 + n15;
          O[(size_t)row * 512 + col] = __float2bfloat16(acc[ti][tj][r]);
        }
  } else {
    bf16* O = (z == 2) ? vpt : (z == 3) ? q2t : k2t;
    const int bb = rowBase >> 10, rowInB = rowBase & 1023;
#pragma unroll
    for (int ti = 0; ti < 4; ++ti)
#pragma unroll
      for (int tj = 0; tj < 4; ++tj) {
        int l0  = rowInB + wm + ti * 16 + quad * 4;
        int col = colBase + wn + tj * 16 + n15;
        ushort4 pk = make_ushort4(us(acc[ti][tj][0]), us(acc[ti][tj][1]),
                                  us(acc[ti][tj][2]), us(acc[ti][tj][3]));
        *reinterpret_cast<ushort4*>(&O[((size_t)bb * DD + col) * SL + l0]) = pk;
      }
  }
}

// ---------- K2: feature-affinity softmax, RPB rows per block ----------
__global__ __launch_bounds__(256) void k_fa(const float* __restrict__ x,
                                            const float* __restrict__ fi_g,
                                            const int* __restrict__ lens,
                                            bf16* __restrict__ fa)
{
  __shared__ __align__(16) float sx[SL * NF];   // 45056 B
  __shared__ float sredS[4][RPB];
  const int tid = threadIdx.x, wave = tid >> 6;
  const int b  = blockIdx.x >> 7;
  const int i0 = (blockIdx.x & 127) * RPB;
  {
    const float4* src = reinterpret_cast<const float4*>(x + (size_t)b * SL * NF);
    float4* dst = reinterpret_cast<float4*>(sx);
#pragma unroll
    for (int it = 0; it < 11; ++it) dst[it * 256 + tid] = src[it * 256 + tid];
  }
  float fiv[NF];
#pragma unroll
  for (int f = 0; f < NF; ++f) fiv[f] = fi_g[f];
  const int len = lens[b];
  __syncthreads();
  float xi[RPB][NF];
#pragma unroll
  for (int i = 0; i < RPB; ++i)
#pragma unroll
    for (int f = 0; f < NF; ++f) xi[i][f] = sx[(i0 + i) * NF + f];
  float e[RPB][4];
  float ps[RPB];
#pragma unroll
  for (int i = 0; i < RPB; ++i) ps[i] = 0.f;
#pragma unroll
  for (int t = 0; t < 4; ++t) {
    const int j = tid + t * 256;
    const bool valid = (t < 2) || (j < len);   // len >= 512 always
    float xj[NF];
#pragma unroll
    for (int f = 0; f < NF; ++f) xj[f] = sx[j * NF + f];
#pragma unroll
    for (int i = 0; i < RPB; ++i) {
      float a = 0.f;
#pragma unroll
      for (int f = 0; f < NF; ++f) a += fabsf(xi[i][f] - xj[f]) * fiv[f];
      float ev = valid ? __expf(a) : 0.f;
      e[i][t] = ev;
      ps[i] += ev;
    }
  }
#pragma unroll
  for (int i = 0; i < RPB; ++i) {
    float wsv = wred_sum(ps[i]);
    if ((tid & 63) == 0) sredS[wave][i] = wsv;
  }
  __syncthreads();
  bf16* out = fa + (size_t)b * SL * SL + (size_t)i0 * SL;
#pragma unroll
  for (int i = 0; i < RPB; ++i) {
    const float inv = 1.f / (sredS[0][i] + sredS[1][i] + sredS[2][i] + sredS[3][i]);
#pragma unroll
    for (int t = 0; t < 4; ++t)
      out[(size_t)i * SL + tid + t * 256] = __float2bfloat16(e[i][t] * inv);
  }
}

// ---------- K3: q2f/k2f = fa @ {q2,k2}; outputs into qq/kk cols 256..511 ----------
__global__ __launch_bounds__(256) void k_famul(const bf16* __restrict__ fa,
                                               const bf16* __restrict__ q2t,
                                               const bf16* __restrict__ k2t,
                                               bf16* __restrict__ qq,
                                               bf16* __restrict__ kk)
{
  __shared__ bf16 smem[4 * 128 * 64];
  const int tid = threadIdx.x, lane = tid & 63, wave = tid >> 6;
  // XCD batch-affinity swizzle: grid (8,2,16) -> XCD m owns batch m
  const int flat = blockIdx.x + 8 * blockIdx.y + 16 * blockIdx.z;
  const int lid  = (flat & 7) * 32 + (flat >> 3);
  const int bx = lid & 7, by = (lid >> 3) & 1, bz = lid >> 4;
  const int b = bz >> 1, which = bz & 1;
  const int iBase = bx * 128, dBase = by * 128;
  const bf16* A  = fa + (size_t)b * SL * SL + (size_t)iBase * SL;
  const bf16* Bm = (which ? k2t : q2t) + (size_t)b * DD * SL + (size_t)dBase * SL;
  f32x4 acc[4][4] = {};
  gemm_core(A, SL, Bm, SL, SL, smem, tid, acc);
  bf16* O = (which ? kk : qq) + (size_t)b * SL * 512 + 256;
  const int n15 = lane & 15, quad = lane >> 4;
  const int wm = (wave >> 1) * 64, wn = (wave & 1) * 64;
#pragma unroll
  for (int ti = 0; ti < 4; ++ti)
#pragma unroll
    for (int tj = 0; tj < 4; ++tj)
#pragma unroll
      for (int r = 0; r < 4; ++r)
        O[(size_t)(iBase + wm + ti * 16 + quad * 4 + r) * 512 +
          dBase + wn + tj * 16 + n15] = __float2bfloat16(acc[ti][tj][r]);
}

// ---------- K4: attn = tanh(mask(qq.kk^T/16)), single K=512 GEMM; dual store ----------
__global__ __launch_bounds__(256) void k_attn(const bf16* __restrict__ qq,
                                              const bf16* __restrict__ kk,
                                              const int* __restrict__ lens,
                                              float* __restrict__ attn_f32,
                                              bf16* __restrict__ attn_b16)
{
  __shared__ bf16 smem[4 * 128 * 64];
  const int tid = threadIdx.x, lane = tid & 63, wave = tid >> 6;
  // XCD batch-affinity swizzle: grid (8,8,8) -> XCD m owns batch m
  const int flat = blockIdx.x + 8 * blockIdx.y + 64 * blockIdx.z;
  const int lid  = (flat & 7) * 64 + (flat >> 3);
  const int bx = lid & 7, by = (lid >> 3) & 7, bz = lid >> 6;
  const int b = bz;
  const int iBase = bx * 128, jBase = by * 128;
  f32x4 acc[4][4] = {};
  gemm_core(qq + ((size_t)b * SL + iBase) * 512, 512,
            kk + ((size_t)b * SL + jBase) * 512, 512, 512, smem, tid, acc);
  const int len = lens[b];
  const int n15 = lane & 15, quad = lane >> 4;
  const int wm = (wave >> 1) * 64, wn = (wave & 1) * 64;
#pragma unroll
  for (int ti = 0; ti < 4; ++ti)
#pragma unroll
    for (int tj = 0; tj < 4; ++tj)
#pragma unroll
      for (int r = 0; r < 4; ++r) {
        int i = iBase + wm + ti * 16 + quad * 4 + r;
        int j = jBase + wn + tj * 16 + n15;
        float vv = (j < len) ? tanhf(acc[ti][tj][r] * (1.f / 16.f)) : 0.f;
        size_t idx = (size_t)b * SL * SL + (size_t)i * SL + j;
        attn_f32[idx] = vv;
        attn_b16[idx] = __float2bfloat16(vv);
      }
}

// ---------- K5: out_pre = attn @ vp (bf16 attn, vp pre-transposed) ----------
__global__ __launch_bounds__(256) void k_av(const bf16* __restrict__ attn,
                                            const bf16* __restrict__ vpt,
                                            bf16* __restrict__ out_pre)
{
  __shared__ bf16 smem[4 * 128 * 64];
  const int tid = threadIdx.x, lane = tid & 63, wave = tid >> 6;
  // XCD batch-affinity swizzle: grid (8,2,8) -> XCD m owns batch m
  const int flat = blockIdx.x + 8 * blockIdx.y + 16 * blockIdx.z;
  const int lid  = (flat & 7) * 16 + (flat >> 3);
  const int bx = lid & 7, by = (lid >> 3) & 1, bz = lid >> 4;
  const int b = bz;
  const int iBase = bx * 128, dBase = by * 128;
  f32x4 acc[4][4] = {};
  gemm_core(attn + (size_t)b * SL * SL + (size_t)iBase * SL, SL,
            vpt  + (size_t)b * DD * SL + (size_t)dBase * SL, SL, SL, smem, tid, acc);
  bf16* O = out_pre + (size_t)b * SL * DD;
  const int n15 = lane & 15, quad = lane >> 4;
  const int wm = (wave >> 1) * 64, wn = (wave & 1) * 64;
#pragma unroll
  for (int ti = 0; ti < 4; ++ti)
#pragma unroll
    for (int tj = 0; tj < 4; ++tj)
#pragma unroll
      for (int r = 0; r < 4; ++r)
        O[(size_t)(iBase + wm + ti * 16 + quad * 4 + r) * DD +
          dBase + wn + tj * 16 + n15] = __float2bfloat16(acc[ti][tj][r]);
}

// ---------- K6: fc projection + residual (f32 out for LN) ----------
__global__ __launch_bounds__(256) void k_fc(const bf16* __restrict__ out_pre,
                                            const float* __restrict__ wfc,
                                            const float* __restrict__ qres,
                                            float* __restrict__ fcout)
{
  __shared__ bf16 smem[4 * 128 * 64];
  const int tid = threadIdx.x, lane = tid & 63, wave = tid >> 6;
  const int rowBase = blockIdx.x * 128, colBase = blockIdx.y * 128;
  f32x4 acc[4][4] = {};
  gemm_core(out_pre + (size_t)rowBase * DD, DD, wfc + (size_t)colBase * DD, DD, DD,
            smem, tid, acc);
  const int n15 = lane & 15, quad = lane >> 4;
  const int wm = (wave >> 1) * 64, wn = (wave & 1) * 64;
#pragma unroll
  for (int ti = 0; ti < 4; ++ti)
#pragma unroll
    for (int tj = 0; tj < 4; ++tj)
#pragma unroll
      for (int r = 0; r < 4; ++r) {
        int row = rowBase + wm + ti * 16 + quad * 4 + r;
        int col = colBase + wn + tj * 16 + n15;
        fcout[(size_t)row * DD + col] = acc[ti][tj][r] + qres[(size_t)row * DD + col];
      }
}

// ---------- K7: LayerNorm over D=256, one block per row, f32 out ----------
__global__ __launch_bounds__(256) void k_ln(const float* __restrict__ fcout,
                                            const float* __restrict__ gam,
                                            const float* __restrict__ bet,
                                            float* __restrict__ outp)
{
  __shared__ float r1[4], r2[4];
  const int r = blockIdx.x, tid = threadIdx.x;
  const float v = fcout[(size_t)r * DD + tid];
  float s = wred_sum(v), ss = wred_sum(v * v);
  if ((tid & 63) == 0) { r1[tid >> 6] = s; r2[tid >> 6] = ss; }
  __syncthreads();
  s  = r1[0] + r1[1] + r1[2] + r1[3];
  ss = r2[0] + r2[1] + r2[2] + r2[3];
  const float mean = s * (1.f / DD);
  const float var  = ss * (1.f / DD) - mean * mean;
  float y = (v - mean) * rsqrtf(var + 1e-6f);
  y = y * gam[tid] + bet[tid];
  outp[(size_t)r * DD + tid] = y;
}

extern "C" void kernel_launch(void* const* d_in, const int* in_sizes, int n_in,
                              void* d_out, int out_size, void* d_ws, size_t ws_size,
                              hipStream_t stream)
{
  const float* q    = (const float*)d_in[0];
  const float* k    = (const float*)d_in[1];
  const float* v    = (const float*)d_in[2];
  const float* x    = (const float*)d_in[3];
  const int*  lens  = (const int*)d_in[4];
  const float* wqs  = (const float*)d_in[5];
  const float* wks  = (const float*)d_in[6];
  const float* wvs  = (const float*)d_in[7];
  const float* wqs2 = (const float*)d_in[8];
  const float* wks2 = (const float*)d_in[9];
  const float* wfc  = (const float*)d_in[10];
  const float* fi   = (const float*)d_in[11];
  const float* gam  = (const float*)d_in[12];
  const float* bet  = (const float*)d_in[13];

  char* w = (char*)d_ws;
  const size_t MB = 1u << 20;
  bf16* qq   = (bf16*)(w + 0 * MB);    // 8MB [b*SL][512]: cols 0-255 qp, 256-511 q2f
  bf16* kk   = (bf16*)(w + 8 * MB);    // 8MB [b*SL][512]: cols 0-255 kp, 256-511 k2f
  bf16* vpt  = (bf16*)(w + 16 * MB);   // 4MB [b][d][l]
  bf16* q2t  = (bf16*)(w + 20 * MB);   // 4MB [b][d][l]
  bf16* k2t  = (bf16*)(w + 24 * MB);   // 4MB [b][d][l]
  bf16* fa   = (bf16*)(w + 28 * MB);   // 16MB; reused as attn_b16 after k_famul
  bf16* attn_b16 = fa;
  bf16* out_pre = q2t;                 // q2t dead after k_famul
  float* fcout  = (float*)(w + 0 * MB); // qq dead after k_attn (8MB f32)

  float* outp  = (float*)d_out;                       // (B,L,D) f32
  float* attnp = outp + (size_t)NB * SL * DD;         // (B,L,L) f32

  dim3 blk(256);
  hipLaunchKernelGGL(k_proj,  dim3(64, 2, 5),  blk, 0, stream,
                     q, k, v, wqs, wks, wvs, wqs2, wks2, qq, kk, vpt, q2t, k2t);
  hipLaunchKernelGGL(k_fa,    dim3(NB * 128),  blk, 0, stream, x, fi, lens, fa);
  hipLaunchKernelGGL(k_famul, dim3(8, 2, 16),  blk, 0, stream, fa, q2t, k2t, qq, kk);
  hipLaunchKernelGGL(k_attn,  dim3(8, 8, 8),   blk, 0, stream,
                     qq, kk, lens, attnp, attn_b16);
  hipLaunchKernelGGL(k_av,    dim3(8, 2, 8),   blk, 0, stream, attn_b16, vpt, out_pre);
  hipLaunchKernelGGL(k_fc,    dim3(64, 2),     blk, 0, stream, out_pre, wfc, q, fcout);
  hipLaunchKernelGGL(k_ln,    dim3(NB * SL),   blk, 0, stream, fcout, gam, bet, outp);
}

// Round 8
// 208.788 us; speedup vs baseline: 1.0995x; 1.0995x over previous
//
#include <hip/hip_runtime.h>
#include <hip/hip_bf16.h>
#include <math.h>

typedef __hip_bfloat16 bf16;
typedef __bf16 bf16x8 __attribute__((ext_vector_type(8)));
typedef float  f32x4  __attribute__((ext_vector_type(4)));

#define NB 8
#define SL 1024
#define DD 256
#define NF 11
#define RPB 8

#define AS_G __attribute__((address_space(1)))
#define AS_L __attribute__((address_space(3)))

// ---------- fragment loaders ----------
__device__ __forceinline__ bf16x8 ldfrag(const bf16* p) {
  return *reinterpret_cast<const bf16x8*>(p);
}
__device__ __forceinline__ bf16x8 ldfrag(const float* p) {
  const float4 a = *reinterpret_cast<const float4*>(p);
  const float4 b = *reinterpret_cast<const float4*>(p + 4);
  bf16x8 r;
  r[0] = (__bf16)a.x; r[1] = (__bf16)a.y; r[2] = (__bf16)a.z; r[3] = (__bf16)a.w;
  r[4] = (__bf16)b.x; r[5] = (__bf16)b.y; r[6] = (__bf16)b.z; r[7] = (__bf16)b.w;
  return r;
}
__device__ __forceinline__ unsigned short us(float f) {
  bf16 h = __float2bfloat16(f);
  return *reinterpret_cast<unsigned short*>(&h);
}

// ---------- stage R rows x 64 k into XOR-swizzled LDS ----------
// f32 source: sync VGPR convert
template<int R>
__device__ __forceinline__ void stage_t(const float* __restrict__ g, int ld,
                                        bf16* __restrict__ s, int tid) {
#pragma unroll
  for (int it = 0; it < R / 32; ++it) {
    const int cid = it * 256 + tid;
    const int row = cid >> 3, c16 = cid & 7;
    bf16x8 v = ldfrag(g + (size_t)row * ld + c16 * 8);
    *reinterpret_cast<bf16x8*>(s + row * 64 + ((c16 ^ (row & 7)) << 3)) = v;
  }
}
// bf16 source: async global_load_lds, swizzle folded into source addr
template<int R>
__device__ __forceinline__ void stage_t(const bf16* __restrict__ g, int ld,
                                        bf16* __restrict__ s, int tid) {
  const int wbase = tid & ~63;
#pragma unroll
  for (int it = 0; it < R / 32; ++it) {
    const int cid = it * 256 + tid;
    const int row = cid >> 3, sc = cid & 7;
    const int c16 = sc ^ (row & 7);
    const bf16* src = g + (size_t)row * ld + c16 * 8;
    bf16* dst = s + (size_t)(it * 256 + wbase) * 8;
    __builtin_amdgcn_global_load_lds((const AS_G void*)src, (AS_L void*)dst, 16, 0, 0);
  }
}

// ---------- 64x128 block tile: 4 waves, each 64(M) x 32(N) ----------
// sA: 64x64 (8KB), sB: 128x64 (16KB)
__device__ __forceinline__ void compute_64x128(const bf16* __restrict__ sA,
                                               const bf16* __restrict__ sB,
                                               int lane, int wave, f32x4 acc[4][2]) {
  const int n15 = lane & 15, quad = lane >> 4;
  const int wn = wave * 32;
#pragma unroll
  for (int kc = 0; kc < 2; ++kc) {
    const int c16 = kc * 4 + quad;
    bf16x8 aF[4], bF[2];
#pragma unroll
    for (int t = 0; t < 4; ++t) {
      const int ra = t * 16 + n15;
      aF[t] = *reinterpret_cast<const bf16x8*>(sA + ra * 64 + ((c16 ^ (ra & 7)) << 3));
    }
#pragma unroll
    for (int t = 0; t < 2; ++t) {
      const int rb = wn + t * 16 + n15;
      bF[t] = *reinterpret_cast<const bf16x8*>(sB + rb * 64 + ((c16 ^ (rb & 7)) << 3));
    }
#pragma unroll
    for (int ti = 0; ti < 4; ++ti)
#pragma unroll
      for (int tj = 0; tj < 2; ++tj)
        acc[ti][tj] = __builtin_amdgcn_mfma_f32_16x16x32_bf16(aF[ti], bF[tj], acc[ti][tj], 0, 0, 0);
  }
}

// ---------- block GEMM: C(64x128) += A(64xK) * B(128xK)^T, single-buffer ----------
template<typename TA, typename TB>
__device__ __forceinline__ void gemm_64x128(const TA* __restrict__ A, int lda,
                                            const TB* __restrict__ B, int ldb, int K,
                                            bf16* s, int tid, f32x4 acc[4][2]) {
  const int lane = tid & 63, wave = tid >> 6;
  bf16* sA = s;          // 4096 elems
  bf16* sB = s + 4096;   // 8192 elems
  for (int k0 = 0; k0 < K; k0 += 64) {
    stage_t<64>(A + k0, lda, sA, tid);
    stage_t<128>(B + k0, ldb, sB, tid);
    __syncthreads();
    compute_64x128(sA, sB, lane, wave, acc);
    __syncthreads();
  }
}

__device__ __forceinline__ float wred_sum(float v) {
#pragma unroll
  for (int o = 32; o > 0; o >>= 1) v += __shfl_xor(v, o, 64);
  return v;
}

// ---------- K0: Wc = w_fc @ w_vs (f32, 256x256) ----------
__global__ __launch_bounds__(256) void k_wc(const float* __restrict__ wfc,
                                            const float* __restrict__ wvs,
                                            float* __restrict__ Wc)
{
  const int o = blockIdx.x, m = threadIdx.x;
  const float* fr = wfc + (size_t)o * DD;
  float acc = 0.f;
#pragma unroll 8
  for (int i = 0; i < DD; ++i)
    acc += fr[i] * wvs[(size_t)i * DD + m];
  Wc[(size_t)o * DD + m] = acc;
}

// ---------- K1: 5 fused projections (z=2 computes vpw = v @ Wc^T) ----------
__global__ __launch_bounds__(256) void k_proj(
    const float* __restrict__ q, const float* __restrict__ k, const float* __restrict__ v,
    const float* __restrict__ wqs, const float* __restrict__ wks, const float* __restrict__ Wc,
    const float* __restrict__ wqs2, const float* __restrict__ wks2,
    bf16* __restrict__ qq, bf16* __restrict__ kk,
    bf16* __restrict__ vpwt, bf16* __restrict__ q2t, bf16* __restrict__ k2t)
{
  __shared__ bf16 smem[12288];
  const int tid = threadIdx.x, lane = tid & 63, wave = tid >> 6;
  const int z = blockIdx.z;
  const float* A = (z == 2) ? v : ((z == 1 || z == 4) ? k : q);
  const float* W = (z == 0) ? wqs : (z == 1) ? wks : (z == 2) ? Wc : (z == 3) ? wqs2 : wks2;
  const int rowBase = blockIdx.x * 64;
  const int colBase = blockIdx.y * 128;
  f32x4 acc[4][2] = {};
  gemm_64x128(A + (size_t)rowBase * DD, DD, W + (size_t)colBase * DD, DD, DD, smem, tid, acc);
  const int n15 = lane & 15, quad = lane >> 4;
  const int wn = wave * 32;
  if (z <= 1) {
    bf16* O = (z == 0) ? qq : kk;
#pragma unroll
    for (int ti = 0; ti < 4; ++ti)
#pragma unroll
      for (int tj = 0; tj < 2; ++tj)
#pragma unroll
        for (int r = 0; r < 4; ++r) {
          int row = rowBase + ti * 16 + quad * 4 + r;
          int col = colBase + wn + tj * 16 + n15;
          O[(size_t)row * 512 + col] = __float2bfloat16(acc[ti][tj][r]);
        }
  } else {
    bf16* O = (z == 2) ? vpwt : (z == 3) ? q2t : k2t;
    const int bb = rowBase >> 10, rowInB = rowBase & 1023;
#pragma unroll
    for (int ti = 0; ti < 4; ++ti)
#pragma unroll
      for (int tj = 0; tj < 2; ++tj) {
        int l0  = rowInB + ti * 16 + quad * 4;
        int col = colBase + wn + tj * 16 + n15;
        ushort4 pk = make_ushort4(us(acc[ti][tj][0]), us(acc[ti][tj][1]),
                                  us(acc[ti][tj][2]), us(acc[ti][tj][3]));
        *reinterpret_cast<ushort4*>(&O[((size_t)bb * DD + col) * SL + l0]) = pk;
      }
  }
}

// ---------- K2: feature-affinity softmax, RPB rows per block ----------
__global__ __launch_bounds__(256) void k_fa(const float* __restrict__ x,
                                            const float* __restrict__ fi_g,
                                            const int* __restrict__ lens,
                                            bf16* __restrict__ fa)
{
  __shared__ __align__(16) float sx[SL * NF];
  __shared__ float sredS[4][RPB];
  const int tid = threadIdx.x, wave = tid >> 6;
  const int b  = blockIdx.x >> 7;
  const int i0 = (blockIdx.x & 127) * RPB;
  {
    const float4* src = reinterpret_cast<const float4*>(x + (size_t)b * SL * NF);
    float4* dst = reinterpret_cast<float4*>(sx);
#pragma unroll
    for (int it = 0; it < 11; ++it) dst[it * 256 + tid] = src[it * 256 + tid];
  }
  float fiv[NF];
#pragma unroll
  for (int f = 0; f < NF; ++f) fiv[f] = fi_g[f];
  const int len = lens[b];
  __syncthreads();
  float xi[RPB][NF];
#pragma unroll
  for (int i = 0; i < RPB; ++i)
#pragma unroll
    for (int f = 0; f < NF; ++f) xi[i][f] = sx[(i0 + i) * NF + f];
  float e[RPB][4];
  float ps[RPB];
#pragma unroll
  for (int i = 0; i < RPB; ++i) ps[i] = 0.f;
#pragma unroll
  for (int t = 0; t < 4; ++t) {
    const int j = tid + t * 256;
    const bool valid = (t < 2) || (j < len);
    float xj[NF];
#pragma unroll
    for (int f = 0; f < NF; ++f) xj[f] = sx[j * NF + f];
#pragma unroll
    for (int i = 0; i < RPB; ++i) {
      float a = 0.f;
#pragma unroll
      for (int f = 0; f < NF; ++f) a += fabsf(xi[i][f] - xj[f]) * fiv[f];
      float ev = valid ? __expf(a) : 0.f;
      e[i][t] = ev;
      ps[i] += ev;
    }
  }
#pragma unroll
  for (int i = 0; i < RPB; ++i) {
    float wsv = wred_sum(ps[i]);
    if ((tid & 63) == 0) sredS[wave][i] = wsv;
  }
  __syncthreads();
  bf16* out = fa + (size_t)b * SL * SL + (size_t)i0 * SL;
#pragma unroll
  for (int i = 0; i < RPB; ++i) {
    const float inv = 1.f / (sredS[0][i] + sredS[1][i] + sredS[2][i] + sredS[3][i]);
#pragma unroll
    for (int t = 0; t < 4; ++t)
      out[(size_t)i * SL + tid + t * 256] = __float2bfloat16(e[i][t] * inv);
  }
}

// ---------- K3: q2f/k2f = fa @ {q2,k2} -> qq/kk cols 256..511 ----------
__global__ __launch_bounds__(256) void k_famul(const bf16* __restrict__ fa,
                                               const bf16* __restrict__ q2t,
                                               const bf16* __restrict__ k2t,
                                               bf16* __restrict__ qq,
                                               bf16* __restrict__ kk)
{
  __shared__ bf16 smem[12288];
  const int tid = threadIdx.x, lane = tid & 63, wave = tid >> 6;
  // grid (16,2,16); swizzle so batch ~ XCD
  const int flat = blockIdx.x + 16 * blockIdx.y + 32 * blockIdx.z;
  const int lid  = (flat & 7) * 64 + (flat >> 3);
  const int bx = lid & 15, by = (lid >> 4) & 1, bz = lid >> 5;
  const int b = bz >> 1, which = bz & 1;
  const int iBase = bx * 64, dBase = by * 128;
  const bf16* A  = fa + (size_t)b * SL * SL + (size_t)iBase * SL;
  const bf16* Bm = (which ? k2t : q2t) + (size_t)b * DD * SL + (size_t)dBase * SL;
  f32x4 acc[4][2] = {};
  gemm_64x128(A, SL, Bm, SL, SL, smem, tid, acc);
  bf16* O = (which ? kk : qq) + (size_t)b * SL * 512 + 256;
  const int n15 = lane & 15, quad = lane >> 4;
  const int wn = wave * 32;
#pragma unroll
  for (int ti = 0; ti < 4; ++ti)
#pragma unroll
    for (int tj = 0; tj < 2; ++tj)
#pragma unroll
      for (int r = 0; r < 4; ++r)
        O[(size_t)(iBase + ti * 16 + quad * 4 + r) * 512 +
          dBase + wn + tj * 16 + n15] = __float2bfloat16(acc[ti][tj][r]);
}

// ---------- K4: attn = tanh(mask(qq.kk^T/16)), K=512; dual store ----------
__global__ __launch_bounds__(256) void k_attn(const bf16* __restrict__ qq,
                                              const bf16* __restrict__ kk,
                                              const int* __restrict__ lens,
                                              float* __restrict__ attn_f32,
                                              bf16* __restrict__ attn_b16)
{
  __shared__ bf16 smem[12288];
  const int tid = threadIdx.x, lane = tid & 63, wave = tid >> 6;
  // grid (16,8,8); swizzle so batch ~ XCD
  const int flat = blockIdx.x + 16 * blockIdx.y + 128 * blockIdx.z;
  const int lid  = (flat & 7) * 128 + (flat >> 3);
  const int bx = lid & 15, by = (lid >> 4) & 7, bz = lid >> 7;
  const int b = bz;
  const int iBase = bx * 64, jBase = by * 128;
  f32x4 acc[4][2] = {};
  gemm_64x128(qq + ((size_t)b * SL + iBase) * 512, 512,
              kk + ((size_t)b * SL + jBase) * 512, 512, 512, smem, tid, acc);
  const int len = lens[b];
  const int n15 = lane & 15, quad = lane >> 4;
  const int wn = wave * 32;
#pragma unroll
  for (int ti = 0; ti < 4; ++ti)
#pragma unroll
    for (int tj = 0; tj < 2; ++tj)
#pragma unroll
      for (int r = 0; r < 4; ++r) {
        int i = iBase + ti * 16 + quad * 4 + r;
        int j = jBase + wn + tj * 16 + n15;
        float vv = (j < len) ? tanhf(acc[ti][tj][r] * (1.f / 16.f)) : 0.f;
        size_t idx = (size_t)b * SL * SL + (size_t)i * SL + j;
        attn_f32[idx] = vv;
        attn_b16[idx] = __float2bfloat16(vv);
      }
}

// ---------- K5: fcout = attn @ vpw + q  (fc folded in via Wc) ----------
__global__ __launch_bounds__(256) void k_av(const bf16* __restrict__ attn,
                                            const bf16* __restrict__ vpwt,
                                            const float* __restrict__ qres,
                                            float* __restrict__ fcout)
{
  __shared__ bf16 smem[12288];
  const int tid = threadIdx.x, lane = tid & 63, wave = tid >> 6;
  // grid (16,2,8); swizzle so batch ~ XCD
  const int flat = blockIdx.x + 16 * blockIdx.y + 32 * blockIdx.z;
  const int lid  = (flat & 7) * 32 + (flat >> 3);
  const int bx = lid & 15, by = (lid >> 4) & 1, bz = lid >> 5;
  const int b = bz;
  const int iBase = bx * 64, dBase = by * 128;
  f32x4 acc[4][2] = {};
  gemm_64x128(attn + (size_t)b * SL * SL + (size_t)iBase * SL, SL,
              vpwt + (size_t)b * DD * SL + (size_t)dBase * SL, SL, SL, smem, tid, acc);
  const int n15 = lane & 15, quad = lane >> 4;
  const int wn = wave * 32;
#pragma unroll
  for (int ti = 0; ti < 4; ++ti)
#pragma unroll
    for (int tj = 0; tj < 2; ++tj)
#pragma unroll
      for (int r = 0; r < 4; ++r) {
        size_t row = (size_t)b * SL + iBase + ti * 16 + quad * 4 + r;
        int col = dBase + wn + tj * 16 + n15;
        fcout[row * DD + col] = acc[ti][tj][r] + qres[row * DD + col];
      }
}

// ---------- K6: LayerNorm over D=256, one block per row, f32 out ----------
__global__ __launch_bounds__(256) void k_ln(const float* __restrict__ fcout,
                                            const float* __restrict__ gam,
                                            const float* __restrict__ bet,
                                            float* __restrict__ outp)
{
  __shared__ float r1[4], r2[4];
  const int r = blockIdx.x, tid = threadIdx.x;
  const float v = fcout[(size_t)r * DD + tid];
  float s = wred_sum(v), ss = wred_sum(v * v);
  if ((tid & 63) == 0) { r1[tid >> 6] = s; r2[tid >> 6] = ss; }
  __syncthreads();
  s  = r1[0] + r1[1] + r1[2] + r1[3];
  ss = r2[0] + r2[1] + r2[2] + r2[3];
  const float mean = s * (1.f / DD);
  const float var  = ss * (1.f / DD) - mean * mean;
  float y = (v - mean) * rsqrtf(var + 1e-6f);
  y = y * gam[tid] + bet[tid];
  outp[(size_t)r * DD + tid] = y;
}

extern "C" void kernel_launch(void* const* d_in, const int* in_sizes, int n_in,
                              void* d_out, int out_size, void* d_ws, size_t ws_size,
                              hipStream_t stream)
{
  const float* q    = (const float*)d_in[0];
  const float* k    = (const float*)d_in[1];
  const float* v    = (const float*)d_in[2];
  const float* x    = (const float*)d_in[3];
  const int*  lens  = (const int*)d_in[4];
  const float* wqs  = (const float*)d_in[5];
  const float* wks  = (const float*)d_in[6];
  const float* wvs  = (const float*)d_in[7];
  const float* wqs2 = (const float*)d_in[8];
  const float* wks2 = (const float*)d_in[9];
  const float* wfc  = (const float*)d_in[10];
  const float* fi   = (const float*)d_in[11];
  const float* gam  = (const float*)d_in[12];
  const float* bet  = (const float*)d_in[13];

  char* w = (char*)d_ws;
  const size_t MB = 1u << 20;
  bf16* qq    = (bf16*)(w + 0 * MB);    // 8MB: cols 0-255 qp, 256-511 q2f
  bf16* kk    = (bf16*)(w + 8 * MB);    // 8MB: cols 0-255 kp, 256-511 k2f
  bf16* vpwt  = (bf16*)(w + 16 * MB);   // 4MB [b][d][l]  (vpw = v @ Wc^T)
  bf16* q2t   = (bf16*)(w + 20 * MB);   // 4MB [b][d][l]
  bf16* k2t   = (bf16*)(w + 24 * MB);   // 4MB [b][d][l]
  bf16* fa    = (bf16*)(w + 28 * MB);   // 16MB; reused as attn_b16 after k_famul
  bf16* attn_b16 = fa;
  float* Wc   = (float*)(w + 28 * MB);  // 256KB; dead once k_proj done (k_fa overwrites)
  float* fcout = (float*)(w + 0 * MB);  // 8MB f32; qq dead after k_attn

  float* outp  = (float*)d_out;                       // (B,L,D) f32
  float* attnp = outp + (size_t)NB * SL * DD;         // (B,L,L) f32

  dim3 blk(256);
  hipLaunchKernelGGL(k_wc,    dim3(256),       blk, 0, stream, wfc, wvs, Wc);
  hipLaunchKernelGGL(k_proj,  dim3(128, 2, 5), blk, 0, stream,
                     q, k, v, wqs, wks, Wc, wqs2, wks2, qq, kk, vpwt, q2t, k2t);
  hipLaunchKernelGGL(k_fa,    dim3(NB * 128),  blk, 0, stream, x, fi, lens, fa);
  hipLaunchKernelGGL(k_famul, dim3(16, 2, 16), blk, 0, stream, fa, q2t, k2t, qq, kk);
  hipLaunchKernelGGL(k_attn,  dim3(16, 8, 8),  blk, 0, stream,
                     qq, kk, lens, attnp, attn_b16);
  hipLaunchKernelGGL(k_av,    dim3(16, 2, 8),  blk, 0, stream, attn_b16, vpwt, q, fcout);
  hipLaunchKernelGGL(k_ln,    dim3(NB * SL),   blk, 0, stream, fcout, gam, bet, outp);
}